// Round 1
// baseline (987.946 us; speedup 1.0000x reference)
//
#include <hip/hip_runtime.h>

constexpr int Dm = 1024;   // model dim
constexpr int Sq = 2048;   // seq len
constexpr int Hh = 16;     // heads
constexpr int Dh = 64;     // head dim
constexpr int Rows = 4096; // B * S

// ---------------- LayerNorm: one block per row ----------------
__global__ __launch_bounds__(256) void ln_kernel(
    const float* __restrict__ x, const float* __restrict__ gamma,
    const float* __restrict__ beta, float* __restrict__ xn) {
  const int row = blockIdx.x;
  const int t = threadIdx.x;
  float4 v = reinterpret_cast<const float4*>(x + (size_t)row * Dm)[t];
  float s = v.x + v.y + v.z + v.w;
  float s2 = v.x * v.x + v.y * v.y + v.z * v.z + v.w * v.w;
#pragma unroll
  for (int off = 32; off > 0; off >>= 1) {
    s += __shfl_down(s, off);
    s2 += __shfl_down(s2, off);
  }
  __shared__ float red[8];
  if ((t & 63) == 0) { red[t >> 6] = s; red[(t >> 6) + 4] = s2; }
  __syncthreads();
  float ts = red[0] + red[1] + red[2] + red[3];
  float ts2 = red[4] + red[5] + red[6] + red[7];
  float mean = ts * (1.0f / Dm);
  float var = ts2 * (1.0f / Dm) - mean * mean;
  float rstd = rsqrtf(var + 1e-5f);
  float4 g = reinterpret_cast<const float4*>(gamma)[t];
  float4 b = reinterpret_cast<const float4*>(beta)[t];
  float4 o;
  o.x = (v.x - mean) * rstd * g.x + b.x;
  o.y = (v.y - mean) * rstd * g.y + b.y;
  o.z = (v.z - mean) * rstd * g.z + b.z;
  o.w = (v.w - mean) * rstd * g.w + b.w;
  reinterpret_cast<float4*>(xn + (size_t)row * Dm)[t] = o;
}

// ---------------- fp32 GEMM, 128x128 tile, BK=16, 8x8 micro-tile ----------------
// MODE 0: C = A @ Bm, scatter into q/k/v [B,H,S,Dh] layout, q scaled by 0.125
// MODE 1: C = A @ Bm + bias -> o0 row-major [Rows, N]
template <int N, int MODE>
__global__ __launch_bounds__(256) void gemm128(
    const float* __restrict__ A, const float* __restrict__ Bm,
    float* __restrict__ o0, float* __restrict__ o1, float* __restrict__ o2,
    const float* __restrict__ bias) {
  __shared__ float As[16][136];  // [k][m] transposed
  __shared__ float Bs[16][136];  // [k][n]
  const int tid = threadIdx.x;
  const int bn = blockIdx.x, bm = blockIdx.y;
  const int ty = tid >> 4, tx = tid & 15;
  float acc[8][8];
#pragma unroll
  for (int i = 0; i < 8; ++i)
#pragma unroll
    for (int j = 0; j < 8; ++j) acc[i][j] = 0.0f;

  const float* Abase = A + (size_t)bm * 128 * Dm;
  const float* Bbase = Bm + (size_t)bn * 128;

  for (int k0 = 0; k0 < Dm; k0 += 16) {
#pragma unroll
    for (int p = 0; p < 2; ++p) {
      int l = tid + p * 256;
      int ar = l >> 2, ak = (l & 3) << 2;
      float4 av = *reinterpret_cast<const float4*>(Abase + (size_t)ar * Dm + k0 + ak);
      As[ak + 0][ar] = av.x; As[ak + 1][ar] = av.y;
      As[ak + 2][ar] = av.z; As[ak + 3][ar] = av.w;
      int br = l >> 5, bc = (l & 31) << 2;
      float4 bv = *reinterpret_cast<const float4*>(Bbase + (size_t)(k0 + br) * N + bc);
      *reinterpret_cast<float4*>(&Bs[br][bc]) = bv;
    }
    __syncthreads();
#pragma unroll
    for (int kk = 0; kk < 16; ++kk) {
      float4 a0 = *reinterpret_cast<const float4*>(&As[kk][ty * 8]);
      float4 a1 = *reinterpret_cast<const float4*>(&As[kk][ty * 8 + 4]);
      float4 b0 = *reinterpret_cast<const float4*>(&Bs[kk][tx * 4]);       // cols tx*4..+3
      float4 b1 = *reinterpret_cast<const float4*>(&Bs[kk][64 + tx * 4]);  // cols 64+tx*4..+3
      float av[8] = {a0.x, a0.y, a0.z, a0.w, a1.x, a1.y, a1.z, a1.w};
      float bv[8] = {b0.x, b0.y, b0.z, b0.w, b1.x, b1.y, b1.z, b1.w};
#pragma unroll
      for (int i = 0; i < 8; ++i)
#pragma unroll
        for (int j = 0; j < 8; ++j)
          acc[i][j] = fmaf(av[i], bv[j], acc[i][j]);
    }
    __syncthreads();
  }

  const int m0 = bm * 128 + ty * 8;
  if (MODE == 0) {
    const int cA = bn * 128 + tx * 4;  // 128-wide tile never straddles q/k/v (1024%128==0)
    const int cB = cA + 64;
    const int which = cA >> 10;
    const int dA = cA & 1023, dB = cB & 1023;
    const int hA = dA >> 6, dhA = dA & 63;
    const int hB = dB >> 6, dhB = dB & 63;
    float* dst = which == 0 ? o0 : (which == 1 ? o1 : o2);
    const float sc = (which == 0) ? 0.125f : 1.0f;
#pragma unroll
    for (int i = 0; i < 8; ++i) {
      int m = m0 + i;
      int bb = m >> 11, ss = m & 2047;
      float4 v0 = {acc[i][0] * sc, acc[i][1] * sc, acc[i][2] * sc, acc[i][3] * sc};
      float4 v1 = {acc[i][4] * sc, acc[i][5] * sc, acc[i][6] * sc, acc[i][7] * sc};
      *reinterpret_cast<float4*>(&dst[(((size_t)bb * Hh + hA) * Sq + ss) * Dh + dhA]) = v0;
      *reinterpret_cast<float4*>(&dst[(((size_t)bb * Hh + hB) * Sq + ss) * Dh + dhB]) = v1;
    }
  } else {
    const int cA = bn * 128 + tx * 4;
    const int cB = cA + 64;
    float4 bias0 = *reinterpret_cast<const float4*>(&bias[cA]);
    float4 bias1 = *reinterpret_cast<const float4*>(&bias[cB]);
#pragma unroll
    for (int i = 0; i < 8; ++i) {
      int m = m0 + i;
      float4 v0 = {acc[i][0] + bias0.x, acc[i][1] + bias0.y,
                   acc[i][2] + bias0.z, acc[i][3] + bias0.w};
      float4 v1 = {acc[i][4] + bias1.x, acc[i][5] + bias1.y,
                   acc[i][6] + bias1.z, acc[i][7] + bias1.w};
      *reinterpret_cast<float4*>(&o0[(size_t)m * N + cA]) = v0;
      *reinterpret_cast<float4*>(&o0[(size_t)m * N + cB]) = v1;
    }
  }
}

// ---------------- flash-style fp32 attention ----------------
// grid (S/64, B*H); block 256. Each thread: 4 q-rows x 4 cols micro-tiles.
__global__ __launch_bounds__(256) void attn_kernel(
    const float* __restrict__ Q, const float* __restrict__ K,
    const float* __restrict__ V, float* __restrict__ O) {
  __shared__ float Qs[64][68];  // [d][qrow]
  __shared__ float Ks[64][68];  // [d][kcol]
  __shared__ float Vs[64][68];  // [kc][dh]
  __shared__ float Ps[64][68];  // [kc][qrow]
  const int tid = threadIdx.x;
  const int qt = blockIdx.x;
  const int bh = blockIdx.y;
  const int qr4 = tid >> 4, kc4 = tid & 15;
  const float* Qb = Q + ((size_t)bh * Sq + qt * 64) * Dh;
  const float* Kb = K + (size_t)bh * Sq * Dh;
  const float* Vb = V + (size_t)bh * Sq * Dh;

#pragma unroll
  for (int p = 0; p < 4; ++p) {
    int l = tid + p * 256;
    int r = l >> 4, c = (l & 15) << 2;
    float4 v = *reinterpret_cast<const float4*>(Qb + (size_t)r * Dh + c);
    Qs[c + 0][r] = v.x; Qs[c + 1][r] = v.y; Qs[c + 2][r] = v.z; Qs[c + 3][r] = v.w;
  }

  float o[4][4];
  float mrun[4], lrun[4];
#pragma unroll
  for (int i = 0; i < 4; ++i) {
    mrun[i] = -1e30f; lrun[i] = 0.0f;
#pragma unroll
    for (int j = 0; j < 4; ++j) o[i][j] = 0.0f;
  }

  for (int kt = 0; kt < Sq / 64; ++kt) {
#pragma unroll
    for (int p = 0; p < 4; ++p) {
      int l = tid + p * 256;
      int r = l >> 4, c = (l & 15) << 2;
      float4 kv = *reinterpret_cast<const float4*>(Kb + (size_t)(kt * 64 + r) * Dh + c);
      Ks[c + 0][r] = kv.x; Ks[c + 1][r] = kv.y; Ks[c + 2][r] = kv.z; Ks[c + 3][r] = kv.w;
      float4 vv = *reinterpret_cast<const float4*>(Vb + (size_t)(kt * 64 + r) * Dh + c);
      *reinterpret_cast<float4*>(&Vs[r][c]) = vv;
    }
    __syncthreads();  // (a) K/V (and first-iter Q) staged

    float p4[4][4];
#pragma unroll
    for (int i = 0; i < 4; ++i)
#pragma unroll
      for (int j = 0; j < 4; ++j) p4[i][j] = 0.0f;
    for (int d = 0; d < 64; ++d) {
      float4 a = *reinterpret_cast<const float4*>(&Qs[d][qr4 * 4]);
      float4 b = *reinterpret_cast<const float4*>(&Ks[d][kc4 * 4]);
      float aa[4] = {a.x, a.y, a.z, a.w};
      float bb[4] = {b.x, b.y, b.z, b.w};
#pragma unroll
      for (int i = 0; i < 4; ++i)
#pragma unroll
        for (int j = 0; j < 4; ++j)
          p4[i][j] = fmaf(aa[i], bb[j], p4[i][j]);
    }

    // online softmax: rows owned redundantly by the 16 lanes sharing qr4
#pragma unroll
    for (int i = 0; i < 4; ++i) {
      float mx = fmaxf(fmaxf(p4[i][0], p4[i][1]), fmaxf(p4[i][2], p4[i][3]));
#pragma unroll
      for (int off = 1; off < 16; off <<= 1) mx = fmaxf(mx, __shfl_xor(mx, off));
      float mnew = fmaxf(mrun[i], mx);
      float corr = __expf(mrun[i] - mnew);
      float s = 0.0f;
#pragma unroll
      for (int j = 0; j < 4; ++j) { p4[i][j] = __expf(p4[i][j] - mnew); s += p4[i][j]; }
#pragma unroll
      for (int off = 1; off < 16; off <<= 1) s += __shfl_xor(s, off);
      lrun[i] = lrun[i] * corr + s;
      mrun[i] = mnew;
#pragma unroll
      for (int j = 0; j < 4; ++j) o[i][j] *= corr;
    }

#pragma unroll
    for (int i = 0; i < 4; ++i)
#pragma unroll
      for (int j = 0; j < 4; ++j)
        Ps[kc4 * 4 + j][qr4 * 4 + i] = p4[i][j];
    __syncthreads();  // (c) P staged (also: everyone done reading Ks)

    for (int kc = 0; kc < 64; ++kc) {
      float4 a = *reinterpret_cast<const float4*>(&Ps[kc][qr4 * 4]);
      float4 v = *reinterpret_cast<const float4*>(&Vs[kc][kc4 * 4]);
      float aa[4] = {a.x, a.y, a.z, a.w};
      float vv4[4] = {v.x, v.y, v.z, v.w};
#pragma unroll
      for (int i = 0; i < 4; ++i)
#pragma unroll
        for (int j = 0; j < 4; ++j)
          o[i][j] = fmaf(aa[i], vv4[j], o[i][j]);
    }
    __syncthreads();  // (d) done with Vs/Ps before next-iter overwrite
  }

  const int b = bh >> 4, h = bh & 15;
#pragma unroll
  for (int i = 0; i < 4; ++i) {
    int srow = qt * 64 + qr4 * 4 + i;
    float inv = 1.0f / lrun[i];
    float4 ov = {o[i][0] * inv, o[i][1] * inv, o[i][2] * inv, o[i][3] * inv};
    *reinterpret_cast<float4*>(&O[((size_t)(b * Sq + srow)) * Dm + h * Dh + kc4 * 4]) = ov;
  }
}

extern "C" void kernel_launch(void* const* d_in, const int* in_sizes, int n_in,
                              void* d_out, int out_size, void* d_ws, size_t ws_size,
                              hipStream_t stream) {
  const float* x = (const float*)d_in[0];
  const float* gamma = (const float*)d_in[1];
  const float* beta = (const float*)d_in[2];
  const float* w_qkv = (const float*)d_in[3];
  const float* w_out = (const float*)d_in[4];
  const float* b_out = (const float*)d_in[5];
  float* out = (float*)d_out;
  float* ws = (float*)d_ws;
  const size_t NT = (size_t)Rows * Dm;  // 4,194,304 floats per buffer
  float* XN = ws;            // [4096,1024] normalized x
  float* Qb = ws + NT;       // [B,H,S,64], pre-scaled by 1/8
  float* Kb = ws + 2 * NT;   // [B,H,S,64]
  float* Vb = ws + 3 * NT;   // [B,H,S,64]
  float* Ob = ws + 4 * NT;   // [4096,1024] attention output (heads merged)
  // total ws use: 5 * 16 MiB = 80 MiB

  ln_kernel<<<dim3(Rows), dim3(256), 0, stream>>>(x, gamma, beta, XN);
  gemm128<3072, 0><<<dim3(24, 32), dim3(256), 0, stream>>>(XN, w_qkv, Qb, Kb, Vb, nullptr);
  attn_kernel<<<dim3(32, 32), dim3(256), 0, stream>>>(Qb, Kb, Vb, Ob);
  gemm128<1024, 1><<<dim3(8, 32), dim3(256), 0, stream>>>(Ob, w_out, out, nullptr, nullptr, b_out);
}

// Round 2
// 736.517 us; speedup vs baseline: 1.3414x; 1.3414x over previous
//
#include <hip/hip_runtime.h>

constexpr int Dm = 1024;   // model dim
constexpr int Sq = 2048;   // seq len
constexpr int Hh = 16;     // heads
constexpr int Dh = 64;     // head dim
constexpr int Rows = 4096; // B * S

typedef __attribute__((ext_vector_type(8))) short bf16x8;
typedef __attribute__((ext_vector_type(4))) float f32x4;

__device__ inline unsigned short f2bf(float f) {
  union { float f; unsigned int u; } v; v.f = f;
  unsigned int r = v.u + 0x7FFFu + ((v.u >> 16) & 1u);
  return (unsigned short)(r >> 16);
}
__device__ inline unsigned int pack2(float a, float b) {
  return (unsigned int)f2bf(a) | ((unsigned int)f2bf(b) << 16);
}

// ---------------- LayerNorm: one block per row ----------------
__global__ __launch_bounds__(256) void ln_kernel(
    const float* __restrict__ x, const float* __restrict__ gamma,
    const float* __restrict__ beta, float* __restrict__ xn) {
  const int row = blockIdx.x;
  const int t = threadIdx.x;
  float4 v = reinterpret_cast<const float4*>(x + (size_t)row * Dm)[t];
  float s = v.x + v.y + v.z + v.w;
  float s2 = v.x * v.x + v.y * v.y + v.z * v.z + v.w * v.w;
#pragma unroll
  for (int off = 32; off > 0; off >>= 1) {
    s += __shfl_down(s, off);
    s2 += __shfl_down(s2, off);
  }
  __shared__ float red[8];
  if ((t & 63) == 0) { red[t >> 6] = s; red[(t >> 6) + 4] = s2; }
  __syncthreads();
  float ts = red[0] + red[1] + red[2] + red[3];
  float ts2 = red[4] + red[5] + red[6] + red[7];
  float mean = ts * (1.0f / Dm);
  float var = ts2 * (1.0f / Dm) - mean * mean;
  float rstd = rsqrtf(var + 1e-5f);
  float4 g = reinterpret_cast<const float4*>(gamma)[t];
  float4 b = reinterpret_cast<const float4*>(beta)[t];
  float4 o;
  o.x = (v.x - mean) * rstd * g.x + b.x;
  o.y = (v.y - mean) * rstd * g.y + b.y;
  o.z = (v.z - mean) * rstd * g.z + b.z;
  o.w = (v.w - mean) * rstd * g.w + b.w;
  reinterpret_cast<float4*>(xn + (size_t)row * Dm)[t] = o;
}

// ---------------- fp32 GEMM, 128x128 tile, BK=16, 8x8 micro-tile ----------------
// MODE 0: C = A @ Bm; emit bf16: q (x0.125) [B,H,S,64], k [B,H,S,64], v transposed [B,H,64,S]
// MODE 1: C = A @ Bm + bias -> oF row-major [Rows, N] fp32
template <int N, int MODE>
__global__ __launch_bounds__(256) void gemm128(
    const float* __restrict__ A, const float* __restrict__ Bm,
    float* __restrict__ oF, unsigned short* __restrict__ qq,
    unsigned short* __restrict__ kk, unsigned short* __restrict__ vv,
    const float* __restrict__ bias) {
  __shared__ float As[16][136];  // [k][m] transposed
  __shared__ float Bs[16][136];  // [k][n]
  const int tid = threadIdx.x;
  const int bn = blockIdx.x, bm = blockIdx.y;
  const int ty = tid >> 4, tx = tid & 15;
  float acc[8][8];
#pragma unroll
  for (int i = 0; i < 8; ++i)
#pragma unroll
    for (int j = 0; j < 8; ++j) acc[i][j] = 0.0f;

  const float* Abase = A + (size_t)bm * 128 * Dm;
  const float* Bbase = Bm + (size_t)bn * 128;

  for (int k0 = 0; k0 < Dm; k0 += 16) {
#pragma unroll
    for (int p = 0; p < 2; ++p) {
      int l = tid + p * 256;
      int ar = l >> 2, ak = (l & 3) << 2;
      float4 av = *reinterpret_cast<const float4*>(Abase + (size_t)ar * Dm + k0 + ak);
      As[ak + 0][ar] = av.x; As[ak + 1][ar] = av.y;
      As[ak + 2][ar] = av.z; As[ak + 3][ar] = av.w;
      int br = l >> 5, bc = (l & 31) << 2;
      float4 bv = *reinterpret_cast<const float4*>(Bbase + (size_t)(k0 + br) * N + bc);
      *reinterpret_cast<float4*>(&Bs[br][bc]) = bv;
    }
    __syncthreads();
#pragma unroll
    for (int kk2 = 0; kk2 < 16; ++kk2) {
      float4 a0 = *reinterpret_cast<const float4*>(&As[kk2][ty * 8]);
      float4 a1 = *reinterpret_cast<const float4*>(&As[kk2][ty * 8 + 4]);
      float4 b0 = *reinterpret_cast<const float4*>(&Bs[kk2][tx * 4]);
      float4 b1 = *reinterpret_cast<const float4*>(&Bs[kk2][64 + tx * 4]);
      float av[8] = {a0.x, a0.y, a0.z, a0.w, a1.x, a1.y, a1.z, a1.w};
      float bv[8] = {b0.x, b0.y, b0.z, b0.w, b1.x, b1.y, b1.z, b1.w};
#pragma unroll
      for (int i = 0; i < 8; ++i)
#pragma unroll
        for (int j = 0; j < 8; ++j)
          acc[i][j] = fmaf(av[i], bv[j], acc[i][j]);
    }
    __syncthreads();
  }

  const int m0 = bm * 128 + ty * 8;
  if (MODE == 0) {
    const int cA = bn * 128 + tx * 4;  // block's 128 cols never straddle q/k/v
    const int which = cA >> 10;
    const int dA = cA & 1023;
    const int dB = dA + 64;
    if (which < 2) {
      unsigned short* dst = (which == 0) ? qq : kk;
      const float sc = (which == 0) ? 0.125f : 1.0f;
      const int hA = dA >> 6, dhA = dA & 63;
      const int hB = dB >> 6, dhB = dB & 63;
#pragma unroll
      for (int i = 0; i < 8; ++i) {
        int m = m0 + i;
        int bb = m >> 11, ss = m & 2047;
        uint2 wa, wb;
        wa.x = pack2(acc[i][0] * sc, acc[i][1] * sc);
        wa.y = pack2(acc[i][2] * sc, acc[i][3] * sc);
        wb.x = pack2(acc[i][4] * sc, acc[i][5] * sc);
        wb.y = pack2(acc[i][6] * sc, acc[i][7] * sc);
        *reinterpret_cast<uint2*>(&dst[(((size_t)bb * Hh + hA) * Sq + ss) * Dh + dhA]) = wa;
        *reinterpret_cast<uint2*>(&dst[(((size_t)bb * Hh + hB) * Sq + ss) * Dh + dhB]) = wb;
      }
    } else {
      // v transposed: [B,H,64,S]
      const int bb = m0 >> 11, ss0 = m0 & 2047;
#pragma unroll
      for (int jj = 0; jj < 8; ++jj) {
        const int col = (jj < 4) ? (dA + jj) : (dA + 60 + jj);  // dB + (jj-4)
        const int h = col >> 6, dh = col & 63;
        uint4 w;
        w.x = pack2(acc[0][jj], acc[1][jj]);
        w.y = pack2(acc[2][jj], acc[3][jj]);
        w.z = pack2(acc[4][jj], acc[5][jj]);
        w.w = pack2(acc[6][jj], acc[7][jj]);
        *reinterpret_cast<uint4*>(&vv[((size_t)(bb * Hh + h) * Dh + dh) * Sq + ss0]) = w;
      }
    }
  } else {
    const int cA = bn * 128 + tx * 4;
    const int cB = cA + 64;
    float4 bias0 = *reinterpret_cast<const float4*>(&bias[cA]);
    float4 bias1 = *reinterpret_cast<const float4*>(&bias[cB]);
#pragma unroll
    for (int i = 0; i < 8; ++i) {
      int m = m0 + i;
      float4 v0 = {acc[i][0] + bias0.x, acc[i][1] + bias0.y,
                   acc[i][2] + bias0.z, acc[i][3] + bias0.w};
      float4 v1 = {acc[i][4] + bias1.x, acc[i][5] + bias1.y,
                   acc[i][6] + bias1.z, acc[i][7] + bias1.w};
      *reinterpret_cast<float4*>(&oF[(size_t)m * N + cA]) = v0;
      *reinterpret_cast<float4*>(&oF[(size_t)m * N + cB]) = v1;
    }
  }
}

// ---------------- bf16 MFMA flash attention ----------------
// grid (S/64, B*H); 256 threads = 4 independent waves, 16 q-rows each.
// No barriers: K/V read straight from global (L2-resident), P transposed
// through per-wave private LDS (in-order within wave).
__global__ __launch_bounds__(256) void attn_mfma(
    const unsigned short* __restrict__ Q, const unsigned short* __restrict__ K,
    const unsigned short* __restrict__ Vt, float* __restrict__ O) {
  __shared__ unsigned short Plds[4][1024];
  const int tid = threadIdx.x;
  const int wv = tid >> 6, lane = tid & 63;
  const int qn = lane & 15, g = lane >> 4;
  const int bh = blockIdx.y;
  const int q0 = blockIdx.x * 64 + wv * 16;
  const unsigned short* Qb = Q + ((size_t)bh * Sq + q0) * Dh;
  const unsigned short* Kb = K + (size_t)bh * Sq * Dh;
  const unsigned short* Vb = Vt + (size_t)bh * Dh * Sq;
  unsigned short* P = &Plds[wv][0];

  // Q A-fragments (two K=32 halves), hoisted
  bf16x8 qf0 = *reinterpret_cast<const bf16x8*>(Qb + qn * Dh + 8 * g);
  bf16x8 qf1 = *reinterpret_cast<const bf16x8*>(Qb + qn * Dh + 32 + 8 * g);

  f32x4 o[4];
  float mrun[4], lrun[4];
#pragma unroll
  for (int t = 0; t < 4; ++t) o[t] = (f32x4){0.f, 0.f, 0.f, 0.f};
#pragma unroll
  for (int r = 0; r < 4; ++r) { mrun[r] = -1e30f; lrun[r] = 0.f; }

  for (int kt = 0; kt < Sq / 64; ++kt) {
    const unsigned short* Kt = Kb + (size_t)kt * 64 * Dh;
    // QK^T: scores s[t] = 16 q-rows x 16 k-cols (t-th group), K over 64 dims
    f32x4 s[4];
#pragma unroll
    for (int t = 0; t < 4; ++t) {
      bf16x8 kf0 = *reinterpret_cast<const bf16x8*>(Kt + (t * 16 + qn) * Dh + 8 * g);
      bf16x8 kf1 = *reinterpret_cast<const bf16x8*>(Kt + (t * 16 + qn) * Dh + 32 + 8 * g);
      f32x4 z = (f32x4){0.f, 0.f, 0.f, 0.f};
      z = __builtin_amdgcn_mfma_f32_16x16x32_bf16(qf0, kf0, z, 0, 0, 0);
      z = __builtin_amdgcn_mfma_f32_16x16x32_bf16(qf1, kf1, z, 0, 0, 0);
      s[t] = z;
    }
    // prefetch V B-fragments (hide global latency under softmax VALU)
    bf16x8 vf[4][2];
#pragma unroll
    for (int t = 0; t < 4; ++t) {
      vf[t][0] = *reinterpret_cast<const bf16x8*>(
          Vb + (size_t)(t * 16 + qn) * Sq + kt * 64 + 8 * g);
      vf[t][1] = *reinterpret_cast<const bf16x8*>(
          Vb + (size_t)(t * 16 + qn) * Sq + kt * 64 + 32 + 8 * g);
    }
    // online softmax (row r lives at q-row 4*g+r; reduce over 16 lanes)
#pragma unroll
    for (int r = 0; r < 4; ++r) {
      float mx = fmaxf(fmaxf(s[0][r], s[1][r]), fmaxf(s[2][r], s[3][r]));
#pragma unroll
      for (int off = 1; off < 16; off <<= 1) mx = fmaxf(mx, __shfl_xor(mx, off));
      float mnew = fmaxf(mrun[r], mx);
      float corr = __expf(mrun[r] - mnew);
      float sum = 0.f;
#pragma unroll
      for (int t = 0; t < 4; ++t) {
        float e = __expf(s[t][r] - mnew);
        s[t][r] = e;
        sum += e;
      }
#pragma unroll
      for (int off = 1; off < 16; off <<= 1) sum += __shfl_xor(sum, off);
      lrun[r] = lrun[r] * corr + sum;
      mrun[r] = mnew;
#pragma unroll
      for (int t = 0; t < 4; ++t) o[t][r] *= corr;
    }
    // P transpose via per-wave LDS, XOR slot swizzle (16B slots)
#pragma unroll
    for (int t = 0; t < 4; ++t)
#pragma unroll
      for (int r = 0; r < 4; ++r) {
        int q = 4 * g + r, k = 16 * t + qn;
        P[q * 64 + (k ^ ((q & 7) << 3))] = f2bf(s[t][r]);
      }
    bf16x8 pf0 = *reinterpret_cast<const bf16x8*>(P + qn * 64 + ((g ^ (qn & 7)) << 3));
    bf16x8 pf1 = *reinterpret_cast<const bf16x8*>(P + qn * 64 + (((4 + g) ^ (qn & 7)) << 3));
    // PV: o[t] += P(16x64) @ V(64x16 cols of group t)
#pragma unroll
    for (int t = 0; t < 4; ++t) {
      o[t] = __builtin_amdgcn_mfma_f32_16x16x32_bf16(pf0, vf[t][0], o[t], 0, 0, 0);
      o[t] = __builtin_amdgcn_mfma_f32_16x16x32_bf16(pf1, vf[t][1], o[t], 0, 0, 0);
    }
  }

  const int b = bh >> 4, hh = bh & 15;
  float inv[4];
#pragma unroll
  for (int r = 0; r < 4; ++r) inv[r] = 1.0f / lrun[r];
#pragma unroll
  for (int t = 0; t < 4; ++t)
#pragma unroll
    for (int r = 0; r < 4; ++r)
      O[((size_t)(b * Sq) + q0 + 4 * g + r) * Dm + hh * Dh + 16 * t + qn] =
          o[t][r] * inv[r];
}

extern "C" void kernel_launch(void* const* d_in, const int* in_sizes, int n_in,
                              void* d_out, int out_size, void* d_ws, size_t ws_size,
                              hipStream_t stream) {
  const float* x = (const float*)d_in[0];
  const float* gamma = (const float*)d_in[1];
  const float* beta = (const float*)d_in[2];
  const float* w_qkv = (const float*)d_in[3];
  const float* w_out = (const float*)d_in[4];
  const float* b_out = (const float*)d_in[5];
  float* out = (float*)d_out;
  float* ws = (float*)d_ws;
  const size_t NT = (size_t)Rows * Dm;  // 4,194,304 elems
  float* XN = ws;                                   // [4096,1024] fp32
  float* Ob = ws + NT;                              // [4096,1024] fp32 attn out
  unsigned short* Qbf = (unsigned short*)(ws + 2 * NT);  // [B,H,S,64] bf16, x0.125
  unsigned short* Kbf = Qbf + NT;                        // [B,H,S,64] bf16
  unsigned short* Vbf = Qbf + 2 * NT;                    // [B,H,64,S] bf16 (transposed)
  // ws use: 2*16MB fp32 + 3*8MB bf16 = 56MB

  ln_kernel<<<dim3(Rows), dim3(256), 0, stream>>>(x, gamma, beta, XN);
  gemm128<3072, 0><<<dim3(24, 32), dim3(256), 0, stream>>>(
      XN, w_qkv, nullptr, Qbf, Kbf, Vbf, nullptr);
  attn_mfma<<<dim3(Sq / 64, 32), dim3(256), 0, stream>>>(Qbf, Kbf, Vbf, Ob);
  gemm128<1024, 1><<<dim3(8, 32), dim3(256), 0, stream>>>(
      Ob, w_out, out, nullptr, nullptr, nullptr, b_out);
}

// Round 3
// 650.863 us; speedup vs baseline: 1.5179x; 1.1316x over previous
//
#include <hip/hip_runtime.h>

constexpr int Dm = 1024;   // model dim
constexpr int Sq = 2048;   // seq len
constexpr int Hh = 16;     // heads
constexpr int Dh = 64;     // head dim
constexpr int Rows = 4096; // B * S

typedef __attribute__((ext_vector_type(8))) short bf16x8;
typedef __attribute__((ext_vector_type(4))) float f32x4;
typedef unsigned short u16;

__device__ inline u16 f2bf(float f) {
  union { float f; unsigned int u; } v; v.f = f;
  unsigned int r = v.u + 0x7FFFu + ((v.u >> 16) & 1u);
  return (u16)(r >> 16);
}
__device__ inline float bf2f(u16 h) {
  union { unsigned int u; float f; } v; v.u = (unsigned int)h << 16;
  return v.f;
}
__device__ inline unsigned int pack2(float a, float b) {
  return (unsigned int)f2bf(a) | ((unsigned int)f2bf(b) << 16);
}

// ---------------- LayerNorm -> split bf16 (hi/lo) ----------------
__global__ __launch_bounds__(256) void ln_kernel(
    const float* __restrict__ x, const float* __restrict__ gamma,
    const float* __restrict__ beta, u16* __restrict__ xh, u16* __restrict__ xl) {
  const int row = blockIdx.x;
  const int t = threadIdx.x;
  float4 v = reinterpret_cast<const float4*>(x + (size_t)row * Dm)[t];
  float s = v.x + v.y + v.z + v.w;
  float s2 = v.x * v.x + v.y * v.y + v.z * v.z + v.w * v.w;
#pragma unroll
  for (int off = 32; off > 0; off >>= 1) {
    s += __shfl_down(s, off);
    s2 += __shfl_down(s2, off);
  }
  __shared__ float red[8];
  if ((t & 63) == 0) { red[t >> 6] = s; red[(t >> 6) + 4] = s2; }
  __syncthreads();
  float ts = red[0] + red[1] + red[2] + red[3];
  float ts2 = red[4] + red[5] + red[6] + red[7];
  float mean = ts * (1.0f / Dm);
  float var = ts2 * (1.0f / Dm) - mean * mean;
  float rstd = rsqrtf(var + 1e-5f);
  float4 g = reinterpret_cast<const float4*>(gamma)[t];
  float4 b = reinterpret_cast<const float4*>(beta)[t];
  float o0 = (v.x - mean) * rstd * g.x + b.x;
  float o1 = (v.y - mean) * rstd * g.y + b.y;
  float o2 = (v.z - mean) * rstd * g.z + b.z;
  float o3 = (v.w - mean) * rstd * g.w + b.w;
  u16 h0 = f2bf(o0), h1 = f2bf(o1), h2 = f2bf(o2), h3 = f2bf(o3);
  uint2 hw = {(unsigned)h0 | ((unsigned)h1 << 16), (unsigned)h2 | ((unsigned)h3 << 16)};
  uint2 lw = {pack2(o0 - bf2f(h0), o1 - bf2f(h1)), pack2(o2 - bf2f(h2), o3 - bf2f(h3))};
  *reinterpret_cast<uint2*>(xh + (size_t)row * Dm + t * 4) = hw;
  *reinterpret_cast<uint2*>(xl + (size_t)row * Dm + t * 4) = lw;
}

// ------------- weight convert: w[K=1024][N] fp32 -> wt_h/wt_l [N][1024] bf16 -------------
__global__ __launch_bounds__(256) void convert_w(
    const float* __restrict__ w, u16* __restrict__ wh, u16* __restrict__ wl, int N) {
  __shared__ float T[64][65];
  const int n0 = blockIdx.x * 64, k0 = blockIdx.y * 64;
  const int t = threadIdx.x;
#pragma unroll
  for (int p = 0; p < 4; ++p) {
    int fid = p * 256 + t;
    int kr = fid >> 4, nn = (fid & 15) * 4;
    float4 v = *reinterpret_cast<const float4*>(w + (size_t)(k0 + kr) * N + n0 + nn);
    T[kr][nn] = v.x; T[kr][nn + 1] = v.y; T[kr][nn + 2] = v.z; T[kr][nn + 3] = v.w;
  }
  __syncthreads();
  const int n = t >> 2, kc = (t & 3) * 16;
  unsigned int hw[8], lw[8];
#pragma unroll
  for (int i = 0; i < 8; ++i) {
    float v0 = T[kc + 2 * i][n], v1 = T[kc + 2 * i + 1][n];
    u16 a = f2bf(v0), b = f2bf(v1);
    hw[i] = (unsigned)a | ((unsigned)b << 16);
    lw[i] = pack2(v0 - bf2f(a), v1 - bf2f(b));
  }
  size_t o = (size_t)(n0 + n) * 1024 + k0 + kc;
  *reinterpret_cast<uint4*>(wh + o) = *reinterpret_cast<uint4*>(&hw[0]);
  *reinterpret_cast<uint4*>(wh + o + 8) = *reinterpret_cast<uint4*>(&hw[4]);
  *reinterpret_cast<uint4*>(wl + o) = *reinterpret_cast<uint4*>(&lw[0]);
  *reinterpret_cast<uint4*>(wl + o + 8) = *reinterpret_cast<uint4*>(&lw[4]);
}

// ---------------- split-bf16 MFMA GEMM ----------------
// C = Ah@B + Al@B with B = Bh+Bl (drops Al@Bl): 3 MFMAs per frag pair.
// A: [M][1024] bf16 hi/lo row-major. Bt: [N][1024] bf16 hi/lo ("B transposed").
// MODE 0 (BM=128): emit q (x0.125)/k [B,H,S,64] bf16, v [B,H,64,S] bf16
// MODE 1: oF[m][c] = acc + bias[c] fp32
template <int BM, int N, int MODE>
__global__ __launch_bounds__(256) void gemm_mfma(
    const u16* __restrict__ Ahg, const u16* __restrict__ Alg,
    const u16* __restrict__ Bhg, const u16* __restrict__ Blg,
    float* __restrict__ oF, u16* __restrict__ qq, u16* __restrict__ kk,
    u16* __restrict__ vv, const float* __restrict__ bias) {
  constexpr int WR = BM / 64;          // waves along M: 2 (BM=128) or 1 (BM=64)
  constexpr int WC = 4 / WR;           // waves along N
  constexpr int NF = 128 / (WC * 16);  // n-frags per wave: 4 or 2
  constexpr int AP = BM / 64;          // uint4 loads/thread per A buffer
  __shared__ u16 Ah[BM * 40], Al[BM * 40], Bh[128 * 40], Bl[128 * 40];
  const int tid = threadIdx.x;
  const int bn = blockIdx.x, bm = blockIdx.y;
  const int wv = tid >> 6, lane = tid & 63;
  const int qn = lane & 15, g = lane >> 4;
  const int wr = wv / WC, wc = wv % WC;
  const int m0 = bm * BM, n0 = bn * 128;

  f32x4 acc[4][NF];
#pragma unroll
  for (int m = 0; m < 4; ++m)
#pragma unroll
    for (int n = 0; n < NF; ++n) acc[m][n] = (f32x4){0.f, 0.f, 0.f, 0.f};

  uint4 ra[2][AP], rb[2][2];
  auto loadRegs = [&](int k0) {
#pragma unroll
    for (int p = 0; p < AP; ++p) {
      int u = p * 256 + tid, row = u >> 2, ch = u & 3;
      ra[0][p] = *reinterpret_cast<const uint4*>(Ahg + (size_t)(m0 + row) * Dm + k0 + ch * 8);
      ra[1][p] = *reinterpret_cast<const uint4*>(Alg + (size_t)(m0 + row) * Dm + k0 + ch * 8);
    }
#pragma unroll
    for (int p = 0; p < 2; ++p) {
      int u = p * 256 + tid, row = u >> 2, ch = u & 3;
      rb[0][p] = *reinterpret_cast<const uint4*>(Bhg + (size_t)(n0 + row) * Dm + k0 + ch * 8);
      rb[1][p] = *reinterpret_cast<const uint4*>(Blg + (size_t)(n0 + row) * Dm + k0 + ch * 8);
    }
  };
  auto storeLDS = [&]() {
#pragma unroll
    for (int p = 0; p < AP; ++p) {
      int u = p * 256 + tid, row = u >> 2, ch = u & 3;
      *reinterpret_cast<uint4*>(&Ah[row * 40 + ch * 8]) = ra[0][p];
      *reinterpret_cast<uint4*>(&Al[row * 40 + ch * 8]) = ra[1][p];
    }
#pragma unroll
    for (int p = 0; p < 2; ++p) {
      int u = p * 256 + tid, row = u >> 2, ch = u & 3;
      *reinterpret_cast<uint4*>(&Bh[row * 40 + ch * 8]) = rb[0][p];
      *reinterpret_cast<uint4*>(&Bl[row * 40 + ch * 8]) = rb[1][p];
    }
  };

  loadRegs(0);
  for (int kt = 0; kt < Dm / 32; ++kt) {
    if (kt) __syncthreads();
    storeLDS();
    __syncthreads();
    if (kt + 1 < Dm / 32) loadRegs((kt + 1) * 32);  // prefetch overlaps MFMAs
    bf16x8 af[2][4], bf[2][NF];
#pragma unroll
    for (int m = 0; m < 4; ++m) {
      af[0][m] = *reinterpret_cast<const bf16x8*>(&Ah[(wr * 64 + m * 16 + qn) * 40 + g * 8]);
      af[1][m] = *reinterpret_cast<const bf16x8*>(&Al[(wr * 64 + m * 16 + qn) * 40 + g * 8]);
    }
#pragma unroll
    for (int n = 0; n < NF; ++n) {
      bf[0][n] = *reinterpret_cast<const bf16x8*>(&Bh[(wc * NF * 16 + n * 16 + qn) * 40 + g * 8]);
      bf[1][n] = *reinterpret_cast<const bf16x8*>(&Bl[(wc * NF * 16 + n * 16 + qn) * 40 + g * 8]);
    }
#pragma unroll
    for (int m = 0; m < 4; ++m)
#pragma unroll
      for (int n = 0; n < NF; ++n) {
        acc[m][n] = __builtin_amdgcn_mfma_f32_16x16x32_bf16(af[0][m], bf[0][n], acc[m][n], 0, 0, 0);
        acc[m][n] = __builtin_amdgcn_mfma_f32_16x16x32_bf16(af[0][m], bf[1][n], acc[m][n], 0, 0, 0);
        acc[m][n] = __builtin_amdgcn_mfma_f32_16x16x32_bf16(af[1][m], bf[0][n], acc[m][n], 0, 0, 0);
      }
  }

  if (MODE == 0) {
    const int which = n0 >> 10;  // uniform: 128-col tile never straddles q/k/v
#pragma unroll
    for (int n = 0; n < NF; ++n) {
      const int c = n0 + wc * NF * 16 + n * 16 + qn;
      const int d = c & 1023, h = d >> 6, dh = d & 63;
#pragma unroll
      for (int m = 0; m < 4; ++m) {
        const int mr0 = m0 + wr * 64 + m * 16 + 4 * g;
        const int bb = mr0 >> 11, ss = mr0 & 2047;
        if (which == 2) {
          uint2 w = {pack2(acc[m][n][0], acc[m][n][1]),
                     pack2(acc[m][n][2], acc[m][n][3])};
          *reinterpret_cast<uint2*>(&vv[(((size_t)bb * Hh + h) * Dh + dh) * Sq + ss]) = w;
        } else {
          u16* dst = (which == 0) ? qq : kk;
          const float sc = (which == 0) ? 0.125f : 1.0f;
#pragma unroll
          for (int r = 0; r < 4; ++r)
            dst[(((size_t)bb * Hh + h) * Sq + (ss + r)) * Dh + dh] =
                f2bf(acc[m][n][r] * sc);
        }
      }
    }
  } else {
#pragma unroll
    for (int n = 0; n < NF; ++n) {
      const int c = n0 + wc * NF * 16 + n * 16 + qn;
      const float bv = bias[c];
#pragma unroll
      for (int m = 0; m < 4; ++m) {
        const int mr0 = m0 + wr * 64 + m * 16 + 4 * g;
#pragma unroll
        for (int r = 0; r < 4; ++r)
          oF[(size_t)(mr0 + r) * N + c] = acc[m][n][r] + bv;
      }
    }
  }
}

// ---------------- bf16 MFMA flash attention (epilogue -> split bf16) ----------------
__global__ __launch_bounds__(256) void attn_mfma(
    const u16* __restrict__ Q, const u16* __restrict__ K,
    const u16* __restrict__ Vt, u16* __restrict__ Oh, u16* __restrict__ Ol) {
  __shared__ u16 Plds[4][1024];
  const int tid = threadIdx.x;
  const int wv = tid >> 6, lane = tid & 63;
  const int qn = lane & 15, g = lane >> 4;
  const int bh = blockIdx.y;
  const int q0 = blockIdx.x * 64 + wv * 16;
  const u16* Qb = Q + ((size_t)bh * Sq + q0) * Dh;
  const u16* Kb = K + (size_t)bh * Sq * Dh;
  const u16* Vb = Vt + (size_t)bh * Dh * Sq;
  u16* P = &Plds[wv][0];

  bf16x8 qf0 = *reinterpret_cast<const bf16x8*>(Qb + qn * Dh + 8 * g);
  bf16x8 qf1 = *reinterpret_cast<const bf16x8*>(Qb + qn * Dh + 32 + 8 * g);

  f32x4 o[4];
  float mrun[4], lrun[4];
#pragma unroll
  for (int t = 0; t < 4; ++t) o[t] = (f32x4){0.f, 0.f, 0.f, 0.f};
#pragma unroll
  for (int r = 0; r < 4; ++r) { mrun[r] = -1e30f; lrun[r] = 0.f; }

  for (int kt = 0; kt < Sq / 64; ++kt) {
    const u16* Kt = Kb + (size_t)kt * 64 * Dh;
    f32x4 s[4];
#pragma unroll
    for (int t = 0; t < 4; ++t) {
      bf16x8 kf0 = *reinterpret_cast<const bf16x8*>(Kt + (t * 16 + qn) * Dh + 8 * g);
      bf16x8 kf1 = *reinterpret_cast<const bf16x8*>(Kt + (t * 16 + qn) * Dh + 32 + 8 * g);
      f32x4 z = (f32x4){0.f, 0.f, 0.f, 0.f};
      z = __builtin_amdgcn_mfma_f32_16x16x32_bf16(qf0, kf0, z, 0, 0, 0);
      z = __builtin_amdgcn_mfma_f32_16x16x32_bf16(qf1, kf1, z, 0, 0, 0);
      s[t] = z;
    }
    bf16x8 vf[4][2];
#pragma unroll
    for (int t = 0; t < 4; ++t) {
      vf[t][0] = *reinterpret_cast<const bf16x8*>(
          Vb + (size_t)(t * 16 + qn) * Sq + kt * 64 + 8 * g);
      vf[t][1] = *reinterpret_cast<const bf16x8*>(
          Vb + (size_t)(t * 16 + qn) * Sq + kt * 64 + 32 + 8 * g);
    }
#pragma unroll
    for (int r = 0; r < 4; ++r) {
      float mx = fmaxf(fmaxf(s[0][r], s[1][r]), fmaxf(s[2][r], s[3][r]));
#pragma unroll
      for (int off = 1; off < 16; off <<= 1) mx = fmaxf(mx, __shfl_xor(mx, off));
      float mnew = fmaxf(mrun[r], mx);
      float corr = __expf(mrun[r] - mnew);
      float sum = 0.f;
#pragma unroll
      for (int t = 0; t < 4; ++t) {
        float e = __expf(s[t][r] - mnew);
        s[t][r] = e;
        sum += e;
      }
#pragma unroll
      for (int off = 1; off < 16; off <<= 1) sum += __shfl_xor(sum, off);
      lrun[r] = lrun[r] * corr + sum;
      mrun[r] = mnew;
#pragma unroll
      for (int t = 0; t < 4; ++t) o[t][r] *= corr;
    }
#pragma unroll
    for (int t = 0; t < 4; ++t)
#pragma unroll
      for (int r = 0; r < 4; ++r) {
        int q = 4 * g + r, k = 16 * t + qn;
        P[q * 64 + (k ^ ((q & 7) << 3))] = f2bf(s[t][r]);
      }
    bf16x8 pf0 = *reinterpret_cast<const bf16x8*>(P + qn * 64 + ((g ^ (qn & 7)) << 3));
    bf16x8 pf1 = *reinterpret_cast<const bf16x8*>(P + qn * 64 + (((4 + g) ^ (qn & 7)) << 3));
#pragma unroll
    for (int t = 0; t < 4; ++t) {
      o[t] = __builtin_amdgcn_mfma_f32_16x16x32_bf16(pf0, vf[t][0], o[t], 0, 0, 0);
      o[t] = __builtin_amdgcn_mfma_f32_16x16x32_bf16(pf1, vf[t][1], o[t], 0, 0, 0);
    }
  }

  const int b = bh >> 4, hh = bh & 15;
  float inv[4];
#pragma unroll
  for (int r = 0; r < 4; ++r) inv[r] = 1.0f / lrun[r];
#pragma unroll
  for (int t = 0; t < 4; ++t)
#pragma unroll
    for (int r = 0; r < 4; ++r) {
      float val = o[t][r] * inv[r];
      size_t idx = ((size_t)(b * Sq) + q0 + 4 * g + r) * Dm + hh * Dh + 16 * t + qn;
      u16 h = f2bf(val);
      Oh[idx] = h;
      Ol[idx] = f2bf(val - bf2f(h));
    }
}

extern "C" void kernel_launch(void* const* d_in, const int* in_sizes, int n_in,
                              void* d_out, int out_size, void* d_ws, size_t ws_size,
                              hipStream_t stream) {
  const float* x = (const float*)d_in[0];
  const float* gamma = (const float*)d_in[1];
  const float* beta = (const float*)d_in[2];
  const float* w_qkv = (const float*)d_in[3];
  const float* w_out = (const float*)d_in[4];
  const float* b_out = (const float*)d_in[5];
  float* out = (float*)d_out;
  u16* W = (u16*)d_ws;
  const size_t NT = (size_t)Rows * Dm;  // 4M elems
  const size_t MT = (size_t)Dm * Dm;    // 1M elems
  u16* xh = W;               // [4096,1024]
  u16* xl = W + NT;
  u16* Qbf = W + 2 * NT;     // [B,H,S,64], x0.125
  u16* Kbf = W + 3 * NT;     // [B,H,S,64]
  u16* Vbf = W + 4 * NT;     // [B,H,64,S]
  u16* Ohh = W + 5 * NT;     // attn out hi [4096,1024]
  u16* Oll = W + 6 * NT;     // attn out lo
  u16* wqh = W + 7 * NT;     // [3072,1024] (w_qkv^T hi)
  u16* wql = wqh + 3 * MT;
  u16* woh = wql + 3 * MT;   // [1024,1024] (w_out^T hi)
  u16* wol = woh + MT;       // total: 7*8MB + 8*2MB = 72MB

  convert_w<<<dim3(48, 16), dim3(256), 0, stream>>>(w_qkv, wqh, wql, 3072);
  convert_w<<<dim3(16, 16), dim3(256), 0, stream>>>(w_out, woh, wol, 1024);
  ln_kernel<<<dim3(Rows), dim3(256), 0, stream>>>(x, gamma, beta, xh, xl);
  gemm_mfma<128, 3072, 0><<<dim3(24, 32), dim3(256), 0, stream>>>(
      xh, xl, wqh, wql, nullptr, Qbf, Kbf, Vbf, nullptr);
  attn_mfma<<<dim3(Sq / 64, 32), dim3(256), 0, stream>>>(Qbf, Kbf, Vbf, Ohh, Oll);
  gemm_mfma<64, 1024, 1><<<dim3(8, 64), dim3(256), 0, stream>>>(
      Ohh, Oll, woh, wol, out, nullptr, nullptr, nullptr, b_out);
}

// Round 5
// 488.641 us; speedup vs baseline: 2.0218x; 1.3320x over previous
//
#include <hip/hip_runtime.h>
#include <hip/hip_bf16.h>

constexpr int Dm = 1024;   // model dim
constexpr int Sq = 2048;   // seq len
constexpr int Hh = 16;     // heads
constexpr int Dh = 64;     // head dim
constexpr int Rows = 4096; // B * S

typedef __attribute__((ext_vector_type(8))) short bf16x8;
typedef __attribute__((ext_vector_type(4))) float f32x4;
typedef __attribute__((ext_vector_type(16))) float f32x16;
typedef unsigned short u16;

__device__ inline u16 f2bf(float f) {
  union { float f; unsigned int u; } v; v.f = f;
  unsigned int r = v.u + 0x7FFFu + ((v.u >> 16) & 1u);
  return (u16)(r >> 16);
}
__device__ inline float bf2f(u16 h) {
  union { unsigned int u; float f; } v; v.u = (unsigned int)h << 16;
  return v.f;
}
__device__ inline unsigned int pack2(float a, float b) {
  return (unsigned int)f2bf(a) | ((unsigned int)f2bf(b) << 16);
}
// HW packed cvt (v_cvt_pk_bf16_f32), RNE
__device__ inline int pkbf(float lo, float hi) {
  float2 f = {lo, hi};
  __hip_bfloat162 h = __float22bfloat162_rn(f);
  union { __hip_bfloat162 h; int i; } u; u.h = h;
  return u.i;
}

// Build one PV B-fragment (4 dwords = 8 bf16 along k) from 8 packed scores.
// Lane semantics: s[BASE+j] = P[q=ln31][k0 + (j&3) + 8*(j>>2) + 4*half].
// Needed: dw[m] = pack(P[q][k0+8*half+2m], P[q][k0+8*half+2m+1]), m=0..3.
// lower lane: [p0,p1, partner_p0,partner_p1]; upper: [partner_p2,partner_p3, p2,p3]
template <int BASE>
__device__ inline void mk_frag(const f32x16 s, const int half, int dw[4]) {
  int p0 = pkbf(s[BASE + 0], s[BASE + 1]);
  int p1 = pkbf(s[BASE + 2], s[BASE + 3]);
  int p2 = pkbf(s[BASE + 4], s[BASE + 5]);
  int p3 = pkbf(s[BASE + 6], s[BASE + 7]);
  int t0 = half ? p0 : p2, t1 = half ? p1 : p3;  // send what partner needs
  int u0 = __shfl_xor(t0, 32), u1 = __shfl_xor(t1, 32);
  dw[0] = half ? u0 : p0;
  dw[1] = half ? u1 : p1;
  dw[2] = half ? p2 : u0;
  dw[3] = half ? p3 : u1;
}

// ---------------- LayerNorm -> split bf16 (hi/lo) ----------------
__global__ __launch_bounds__(256) void ln_kernel(
    const float* __restrict__ x, const float* __restrict__ gamma,
    const float* __restrict__ beta, u16* __restrict__ xh, u16* __restrict__ xl) {
  const int row = blockIdx.x;
  const int t = threadIdx.x;
  float4 v = reinterpret_cast<const float4*>(x + (size_t)row * Dm)[t];
  float s = v.x + v.y + v.z + v.w;
  float s2 = v.x * v.x + v.y * v.y + v.z * v.z + v.w * v.w;
#pragma unroll
  for (int off = 32; off > 0; off >>= 1) {
    s += __shfl_down(s, off);
    s2 += __shfl_down(s2, off);
  }
  __shared__ float red[8];
  if ((t & 63) == 0) { red[t >> 6] = s; red[(t >> 6) + 4] = s2; }
  __syncthreads();
  float ts = red[0] + red[1] + red[2] + red[3];
  float ts2 = red[4] + red[5] + red[6] + red[7];
  float mean = ts * (1.0f / Dm);
  float var = ts2 * (1.0f / Dm) - mean * mean;
  float rstd = rsqrtf(var + 1e-5f);
  float4 g = reinterpret_cast<const float4*>(gamma)[t];
  float4 b = reinterpret_cast<const float4*>(beta)[t];
  float o0 = (v.x - mean) * rstd * g.x + b.x;
  float o1 = (v.y - mean) * rstd * g.y + b.y;
  float o2 = (v.z - mean) * rstd * g.z + b.z;
  float o3 = (v.w - mean) * rstd * g.w + b.w;
  u16 h0 = f2bf(o0), h1 = f2bf(o1), h2 = f2bf(o2), h3 = f2bf(o3);
  uint2 hw = {(unsigned)h0 | ((unsigned)h1 << 16), (unsigned)h2 | ((unsigned)h3 << 16)};
  uint2 lw = {pack2(o0 - bf2f(h0), o1 - bf2f(h1)), pack2(o2 - bf2f(h2), o3 - bf2f(h3))};
  *reinterpret_cast<uint2*>(xh + (size_t)row * Dm + t * 4) = hw;
  *reinterpret_cast<uint2*>(xl + (size_t)row * Dm + t * 4) = lw;
}

// ------------- weight convert: w[K=1024][N] fp32 -> wt_h/wt_l [N][1024] bf16 -------------
__global__ __launch_bounds__(256) void convert_w(
    const float* __restrict__ w, u16* __restrict__ wh, u16* __restrict__ wl, int N) {
  __shared__ float T[64][65];
  const int n0 = blockIdx.x * 64, k0 = blockIdx.y * 64;
  const int t = threadIdx.x;
#pragma unroll
  for (int p = 0; p < 4; ++p) {
    int fid = p * 256 + t;
    int kr = fid >> 4, nn = (fid & 15) * 4;
    float4 v = *reinterpret_cast<const float4*>(w + (size_t)(k0 + kr) * N + n0 + nn);
    T[kr][nn] = v.x; T[kr][nn + 1] = v.y; T[kr][nn + 2] = v.z; T[kr][nn + 3] = v.w;
  }
  __syncthreads();
  const int n = t >> 2, kc = (t & 3) * 16;
  unsigned int hw[8], lw[8];
#pragma unroll
  for (int i = 0; i < 8; ++i) {
    float v0 = T[kc + 2 * i][n], v1 = T[kc + 2 * i + 1][n];
    u16 a = f2bf(v0), b = f2bf(v1);
    hw[i] = (unsigned)a | ((unsigned)b << 16);
    lw[i] = pack2(v0 - bf2f(a), v1 - bf2f(b));
  }
  size_t o = (size_t)(n0 + n) * 1024 + k0 + kc;
  *reinterpret_cast<uint4*>(wh + o) = *reinterpret_cast<uint4*>(&hw[0]);
  *reinterpret_cast<uint4*>(wh + o + 8) = *reinterpret_cast<uint4*>(&hw[4]);
  *reinterpret_cast<uint4*>(wl + o) = *reinterpret_cast<uint4*>(&lw[0]);
  *reinterpret_cast<uint4*>(wl + o + 8) = *reinterpret_cast<uint4*>(&lw[4]);
}

// ---------------- split-bf16 MFMA GEMM ----------------
template <int BM, int N, int MODE>
__global__ __launch_bounds__(256) void gemm_mfma(
    const u16* __restrict__ Ahg, const u16* __restrict__ Alg,
    const u16* __restrict__ Bhg, const u16* __restrict__ Blg,
    float* __restrict__ oF, u16* __restrict__ qq, u16* __restrict__ kk,
    u16* __restrict__ vv, const float* __restrict__ bias) {
  constexpr int WR = BM / 64;
  constexpr int WC = 4 / WR;
  constexpr int NF = 128 / (WC * 16);
  constexpr int AP = BM / 64;
  __shared__ u16 Ah[BM * 40], Al[BM * 40], Bh[128 * 40], Bl[128 * 40];
  const int tid = threadIdx.x;
  const int bn = blockIdx.x, bm = blockIdx.y;
  const int wv = tid >> 6, lane = tid & 63;
  const int qn = lane & 15, g = lane >> 4;
  const int wr = wv / WC, wc = wv % WC;
  const int m0 = bm * BM, n0 = bn * 128;

  f32x4 acc[4][NF];
#pragma unroll
  for (int m = 0; m < 4; ++m)
#pragma unroll
    for (int n = 0; n < NF; ++n) acc[m][n] = (f32x4){0.f, 0.f, 0.f, 0.f};

  uint4 ra[2][AP], rb[2][2];
  auto loadRegs = [&](int k0) {
#pragma unroll
    for (int p = 0; p < AP; ++p) {
      int u = p * 256 + tid, row = u >> 2, ch = u & 3;
      ra[0][p] = *reinterpret_cast<const uint4*>(Ahg + (size_t)(m0 + row) * Dm + k0 + ch * 8);
      ra[1][p] = *reinterpret_cast<const uint4*>(Alg + (size_t)(m0 + row) * Dm + k0 + ch * 8);
    }
#pragma unroll
    for (int p = 0; p < 2; ++p) {
      int u = p * 256 + tid, row = u >> 2, ch = u & 3;
      rb[0][p] = *reinterpret_cast<const uint4*>(Bhg + (size_t)(n0 + row) * Dm + k0 + ch * 8);
      rb[1][p] = *reinterpret_cast<const uint4*>(Blg + (size_t)(n0 + row) * Dm + k0 + ch * 8);
    }
  };
  auto storeLDS = [&]() {
#pragma unroll
    for (int p = 0; p < AP; ++p) {
      int u = p * 256 + tid, row = u >> 2, ch = u & 3;
      *reinterpret_cast<uint4*>(&Ah[row * 40 + ch * 8]) = ra[0][p];
      *reinterpret_cast<uint4*>(&Al[row * 40 + ch * 8]) = ra[1][p];
    }
#pragma unroll
    for (int p = 0; p < 2; ++p) {
      int u = p * 256 + tid, row = u >> 2, ch = u & 3;
      *reinterpret_cast<uint4*>(&Bh[row * 40 + ch * 8]) = rb[0][p];
      *reinterpret_cast<uint4*>(&Bl[row * 40 + ch * 8]) = rb[1][p];
    }
  };

  loadRegs(0);
  for (int kt = 0; kt < Dm / 32; ++kt) {
    if (kt) __syncthreads();
    storeLDS();
    __syncthreads();
    if (kt + 1 < Dm / 32) loadRegs((kt + 1) * 32);
    bf16x8 af[2][4], bf[2][NF];
#pragma unroll
    for (int m = 0; m < 4; ++m) {
      af[0][m] = *reinterpret_cast<const bf16x8*>(&Ah[(wr * 64 + m * 16 + qn) * 40 + g * 8]);
      af[1][m] = *reinterpret_cast<const bf16x8*>(&Al[(wr * 64 + m * 16 + qn) * 40 + g * 8]);
    }
#pragma unroll
    for (int n = 0; n < NF; ++n) {
      bf[0][n] = *reinterpret_cast<const bf16x8*>(&Bh[(wc * NF * 16 + n * 16 + qn) * 40 + g * 8]);
      bf[1][n] = *reinterpret_cast<const bf16x8*>(&Bl[(wc * NF * 16 + n * 16 + qn) * 40 + g * 8]);
    }
#pragma unroll
    for (int m = 0; m < 4; ++m)
#pragma unroll
      for (int n = 0; n < NF; ++n) {
        acc[m][n] = __builtin_amdgcn_mfma_f32_16x16x32_bf16(af[0][m], bf[0][n], acc[m][n], 0, 0, 0);
        acc[m][n] = __builtin_amdgcn_mfma_f32_16x16x32_bf16(af[0][m], bf[1][n], acc[m][n], 0, 0, 0);
        acc[m][n] = __builtin_amdgcn_mfma_f32_16x16x32_bf16(af[1][m], bf[0][n], acc[m][n], 0, 0, 0);
      }
  }

  if (MODE == 0) {
    const int which = n0 >> 10;
#pragma unroll
    for (int n = 0; n < NF; ++n) {
      const int c = n0 + wc * NF * 16 + n * 16 + qn;
      const int d = c & 1023, h = d >> 6, dh = d & 63;
#pragma unroll
      for (int m = 0; m < 4; ++m) {
        const int mr0 = m0 + wr * 64 + m * 16 + 4 * g;
        const int bb = mr0 >> 11, ss = mr0 & 2047;
        if (which == 2) {
          uint2 w = {pack2(acc[m][n][0], acc[m][n][1]),
                     pack2(acc[m][n][2], acc[m][n][3])};
          *reinterpret_cast<uint2*>(&vv[(((size_t)bb * Hh + h) * Dh + dh) * Sq + ss]) = w;
        } else {
          u16* dst = (which == 0) ? qq : kk;
          const float sc = (which == 0) ? 0.125f : 1.0f;
#pragma unroll
          for (int r = 0; r < 4; ++r)
            dst[(((size_t)bb * Hh + h) * Sq + (ss + r)) * Dh + dh] =
                f2bf(acc[m][n][r] * sc);
        }
      }
    }
  } else {
#pragma unroll
    for (int n = 0; n < NF; ++n) {
      const int c = n0 + wc * NF * 16 + n * 16 + qn;
      const float bv = bias[c];
#pragma unroll
      for (int m = 0; m < 4; ++m) {
        const int mr0 = m0 + wr * 64 + m * 16 + 4 * g;
#pragma unroll
        for (int r = 0; r < 4; ++r)
          oF[(size_t)(mr0 + r) * N + c] = acc[m][n][r] + bv;
      }
    }
  }
}

// ---------------- swapped-operand 32x32 MFMA flash attention ----------------
// Zero LDS, zero barriers. 4 waves x 32 q-rows; KVBLK=64 (two 32-row subtiles).
// S^T = K.Q^T via mfma(K-rows, Q-rows): lane holds scores of ONE q-row (q=ln31)
// at k = (reg&3)+8*(reg>>2)+4*half -> softmax is in-lane + one shfl_xor(32).
// P^T B-frags built in-register via cvt_pk + shfl_xor(32) exchange.
// PV computes O^T = V^T.P^T (Vt layout [B,H,64,S] gives contiguous V frags).
__global__ __launch_bounds__(256, 2) void attn_mfma32(
    const u16* __restrict__ Q, const u16* __restrict__ K,
    const u16* __restrict__ Vt, u16* __restrict__ Oh, u16* __restrict__ Ol) {
  const int tid = threadIdx.x;
  const int wv = tid >> 6, lane = tid & 63;
  const int ln31 = lane & 31, half = lane >> 5;
  // T1 bijective XCD swizzle: 512 wgs, chunks of 64 -> each XCD sees 4 heads
  const int n = (blockIdx.x & 7) * 64 + (blockIdx.x >> 3);
  const int bh = n >> 4, qt = n & 15;
  const int q0 = qt * 128 + wv * 32;
  const u16* Qb = Q + ((size_t)bh * Sq + q0) * Dh;
  const u16* Kb = K + (size_t)bh * Sq * Dh;
  const u16* Vb = Vt + (size_t)bh * Dh * Sq;

  // Q fragments (B-operand: rows = q, contraction = 8*half+i), 4 d-chunks
  bf16x8 qf[4];
#pragma unroll
  for (int c = 0; c < 4; ++c)
    qf[c] = *reinterpret_cast<const bf16x8*>(Qb + ln31 * Dh + c * 16 + 8 * half);

  f32x16 o0, o1;  // O^T accumulators: dh 0-31 / 32-63, col = own q
#pragma unroll
  for (int j = 0; j < 16; ++j) { o0[j] = 0.f; o1[j] = 0.f; }
  float mrun = -1e30f, lrun = 0.f;

  // K fragments for kt=0
  bf16x8 kf[2][4];
#pragma unroll
  for (int sub = 0; sub < 2; ++sub)
#pragma unroll
    for (int c = 0; c < 4; ++c)
      kf[sub][c] = *reinterpret_cast<const bf16x8*>(
          Kb + (size_t)(sub * 32 + ln31) * Dh + c * 16 + 8 * half);

  for (int kt = 0; kt < Sq / 64; ++kt) {
    // QK^T: s_sub[reg] = S[k = 64kt+32sub+(reg&3)+8(reg>>2)+4half][q = ln31]
    f32x16 s0, s1;
#pragma unroll
    for (int j = 0; j < 16; ++j) { s0[j] = 0.f; s1[j] = 0.f; }
#pragma unroll
    for (int c = 0; c < 4; ++c) {
      s0 = __builtin_amdgcn_mfma_f32_32x32x16_bf16(kf[0][c], qf[c], s0, 0, 0, 0);
      s1 = __builtin_amdgcn_mfma_f32_32x32x16_bf16(kf[1][c], qf[c], s1, 0, 0, 0);
    }
    // V fragments (in flight during softmax)
    bf16x8 vf[2][4];
#pragma unroll
    for (int h2 = 0; h2 < 2; ++h2)
#pragma unroll
      for (int c = 0; c < 4; ++c)
        vf[h2][c] = *reinterpret_cast<const bf16x8*>(
            Vb + (size_t)(h2 * 32 + ln31) * Sq + kt * 64 + c * 16 + 8 * half);
    // online softmax: in-lane over 32 + one cross-half exchange
    float mx = s0[0];
#pragma unroll
    for (int j = 1; j < 16; ++j) mx = fmaxf(mx, s0[j]);
#pragma unroll
    for (int j = 0; j < 16; ++j) mx = fmaxf(mx, s1[j]);
    mx = fmaxf(mx, __shfl_xor(mx, 32));
    float mnew = fmaxf(mrun, mx);
    float corr = __expf(mrun - mnew);
    float sum = 0.f;
#pragma unroll
    for (int j = 0; j < 16; ++j) { float e = __expf(s0[j] - mnew); s0[j] = e; sum += e; }
#pragma unroll
    for (int j = 0; j < 16; ++j) { float e = __expf(s1[j] - mnew); s1[j] = e; sum += e; }
    sum += __shfl_xor(sum, 32);
    lrun = lrun * corr + sum;
    mrun = mnew;
#pragma unroll
    for (int j = 0; j < 16; ++j) { o0[j] *= corr; o1[j] *= corr; }
    // P^T -> bf16 B-fragments (chunk c covers k = c*16..c*16+15)
    int dw[4][4];
    mk_frag<0>(s0, half, dw[0]);
    mk_frag<8>(s0, half, dw[1]);
    mk_frag<0>(s1, half, dw[2]);
    mk_frag<8>(s1, half, dw[3]);
    // prefetch K for kt+1 (hidden under PV MFMAs)
    if (kt + 1 < Sq / 64) {
      const u16* Kn = Kb + (size_t)(kt + 1) * 64 * Dh;
#pragma unroll
      for (int sub = 0; sub < 2; ++sub)
#pragma unroll
        for (int c = 0; c < 4; ++c)
          kf[sub][c] = *reinterpret_cast<const bf16x8*>(
              Kn + (size_t)(sub * 32 + ln31) * Dh + c * 16 + 8 * half);
    }
    // PV: O^T += V^T . P^T
#pragma unroll
    for (int c = 0; c < 4; ++c) {
      union { int4 i; bf16x8 b; } u;
      u.i = make_int4(dw[c][0], dw[c][1], dw[c][2], dw[c][3]);
      o0 = __builtin_amdgcn_mfma_f32_32x32x16_bf16(vf[0][c], u.b, o0, 0, 0, 0);
      o1 = __builtin_amdgcn_mfma_f32_32x32x16_bf16(vf[1][c], u.b, o1, 0, 0, 0);
    }
  }

  // epilogue: lane owns q = ln31, dh rows h2*32 + 8rg + 4half (+0..3)
  const float inv = 1.0f / lrun;
  const int b = bh >> 4, hh = bh & 15;
  u16* oph = Oh + ((size_t)(b * Sq) + q0 + ln31) * Dm + hh * 64;
  u16* opl = Ol + ((size_t)(b * Sq) + q0 + ln31) * Dm + hh * 64;
#pragma unroll
  for (int h2 = 0; h2 < 2; ++h2) {
#pragma unroll
    for (int rg = 0; rg < 4; ++rg) {
      const int dh = h2 * 32 + 8 * rg + 4 * half;
      float v0, v1, v2, v3;
      if (h2 == 0) {
        v0 = o0[4 * rg] * inv; v1 = o0[4 * rg + 1] * inv;
        v2 = o0[4 * rg + 2] * inv; v3 = o0[4 * rg + 3] * inv;
      } else {
        v0 = o1[4 * rg] * inv; v1 = o1[4 * rg + 1] * inv;
        v2 = o1[4 * rg + 2] * inv; v3 = o1[4 * rg + 3] * inv;
      }
      u16 h0 = f2bf(v0), h1 = f2bf(v1), h2b = f2bf(v2), h3 = f2bf(v3);
      uint2 hw = {(unsigned)h0 | ((unsigned)h1 << 16),
                  (unsigned)h2b | ((unsigned)h3 << 16)};
      uint2 lw = {pack2(v0 - bf2f(h0), v1 - bf2f(h1)),
                  pack2(v2 - bf2f(h2b), v3 - bf2f(h3))};
      *reinterpret_cast<uint2*>(oph + dh) = hw;
      *reinterpret_cast<uint2*>(opl + dh) = lw;
    }
  }
}

extern "C" void kernel_launch(void* const* d_in, const int* in_sizes, int n_in,
                              void* d_out, int out_size, void* d_ws, size_t ws_size,
                              hipStream_t stream) {
  const float* x = (const float*)d_in[0];
  const float* gamma = (const float*)d_in[1];
  const float* beta = (const float*)d_in[2];
  const float* w_qkv = (const float*)d_in[3];
  const float* w_out = (const float*)d_in[4];
  const float* b_out = (const float*)d_in[5];
  float* out = (float*)d_out;
  u16* W = (u16*)d_ws;
  const size_t NT = (size_t)Rows * Dm;  // 4M elems
  const size_t MT = (size_t)Dm * Dm;    // 1M elems
  u16* xh = W;
  u16* xl = W + NT;
  u16* Qbf = W + 2 * NT;     // [B,H,S,64], x0.125
  u16* Kbf = W + 3 * NT;     // [B,H,S,64]
  u16* Vbf = W + 4 * NT;     // [B,H,64,S]
  u16* Ohh = W + 5 * NT;     // attn out hi [4096,1024]
  u16* Oll = W + 6 * NT;     // attn out lo
  u16* wqh = W + 7 * NT;     // [3072,1024]
  u16* wql = wqh + 3 * MT;
  u16* woh = wql + 3 * MT;   // [1024,1024]
  u16* wol = woh + MT;

  convert_w<<<dim3(48, 16), dim3(256), 0, stream>>>(w_qkv, wqh, wql, 3072);
  convert_w<<<dim3(16, 16), dim3(256), 0, stream>>>(w_out, woh, wol, 1024);
  ln_kernel<<<dim3(Rows), dim3(256), 0, stream>>>(x, gamma, beta, xh, xl);
  gemm_mfma<128, 3072, 0><<<dim3(24, 32), dim3(256), 0, stream>>>(
      xh, xl, wqh, wql, nullptr, Qbf, Kbf, Vbf, nullptr);
  attn_mfma32<<<dim3(512), dim3(256), 0, stream>>>(Qbf, Kbf, Vbf, Ohh, Oll);
  gemm_mfma<64, 1024, 1><<<dim3(8, 64), dim3(256), 0, stream>>>(
      Ohh, Oll, woh, wol, out, nullptr, nullptr, nullptr, b_out);
}

// Round 6
// 267.943 us; speedup vs baseline: 3.6871x; 1.8237x over previous
//
#include <hip/hip_runtime.h>
#include <hip/hip_bf16.h>

constexpr int Dm = 1024;   // model dim
constexpr int Sq = 2048;   // seq len
constexpr int Hh = 16;     // heads
constexpr int Dh = 64;     // head dim
constexpr int Rows = 4096; // B * S

typedef __attribute__((ext_vector_type(8))) short bf16x8;
typedef __attribute__((ext_vector_type(4))) float f32x4;
typedef __attribute__((ext_vector_type(16))) float f32x16;
typedef unsigned short u16;

__device__ inline u16 f2bf(float f) {
  union { float f; unsigned int u; } v; v.f = f;
  unsigned int r = v.u + 0x7FFFu + ((v.u >> 16) & 1u);
  return (u16)(r >> 16);
}
__device__ inline float bf2f(u16 h) {
  union { unsigned int u; float f; } v; v.u = (unsigned int)h << 16;
  return v.f;
}
__device__ inline unsigned int pack2(float a, float b) {
  return (unsigned int)f2bf(a) | ((unsigned int)f2bf(b) << 16);
}
// HW packed cvt (v_cvt_pk_bf16_f32), RNE
__device__ inline int pkbf(float lo, float hi) {
  float2 f = {lo, hi};
  __hip_bfloat162 h = __float22bfloat162_rn(f);
  union { __hip_bfloat162 h; int i; } u; u.h = h;
  return u.i;
}
// async global->LDS, 16B per lane; lds base must be wave-uniform (HW: base+lane*16)
__device__ __forceinline__ void gload16(u16* lds, const u16* g) {
  __builtin_amdgcn_global_load_lds(
      (const __attribute__((address_space(1))) unsigned int*)g,
      (__attribute__((address_space(3))) unsigned int*)lds, 16, 0, 0);
}

// Build one PV B-fragment (4 dwords = 8 bf16 along k) from 8 packed scores.
// Lane semantics: s[BASE+j] = P[q=ln31][k0 + (j&3) + 8*(j>>2) + 4*half].
// Needed: dw[m] = pack(P[q][k0+8*half+2m], P[q][k0+8*half+2m+1]), m=0..3.
template <int BASE>
__device__ inline void mk_frag(const f32x16 s, const int half, int dw[4]) {
  int p0 = pkbf(s[BASE + 0], s[BASE + 1]);
  int p1 = pkbf(s[BASE + 2], s[BASE + 3]);
  int p2 = pkbf(s[BASE + 4], s[BASE + 5]);
  int p3 = pkbf(s[BASE + 6], s[BASE + 7]);
  int t0 = half ? p0 : p2, t1 = half ? p1 : p3;  // send what partner needs
  int u0 = __shfl_xor(t0, 32), u1 = __shfl_xor(t1, 32);
  dw[0] = half ? u0 : p0;
  dw[1] = half ? u1 : p1;
  dw[2] = half ? p2 : u0;
  dw[3] = half ? p3 : u1;
}

// ---------------- LayerNorm -> split bf16 (hi/lo) ----------------
__global__ __launch_bounds__(256) void ln_kernel(
    const float* __restrict__ x, const float* __restrict__ gamma,
    const float* __restrict__ beta, u16* __restrict__ xh, u16* __restrict__ xl) {
  const int row = blockIdx.x;
  const int t = threadIdx.x;
  float4 v = reinterpret_cast<const float4*>(x + (size_t)row * Dm)[t];
  float s = v.x + v.y + v.z + v.w;
  float s2 = v.x * v.x + v.y * v.y + v.z * v.z + v.w * v.w;
#pragma unroll
  for (int off = 32; off > 0; off >>= 1) {
    s += __shfl_down(s, off);
    s2 += __shfl_down(s2, off);
  }
  __shared__ float red[8];
  if ((t & 63) == 0) { red[t >> 6] = s; red[(t >> 6) + 4] = s2; }
  __syncthreads();
  float ts = red[0] + red[1] + red[2] + red[3];
  float ts2 = red[4] + red[5] + red[6] + red[7];
  float mean = ts * (1.0f / Dm);
  float var = ts2 * (1.0f / Dm) - mean * mean;
  float rstd = rsqrtf(var + 1e-5f);
  float4 g = reinterpret_cast<const float4*>(gamma)[t];
  float4 b = reinterpret_cast<const float4*>(beta)[t];
  float o0 = (v.x - mean) * rstd * g.x + b.x;
  float o1 = (v.y - mean) * rstd * g.y + b.y;
  float o2 = (v.z - mean) * rstd * g.z + b.z;
  float o3 = (v.w - mean) * rstd * g.w + b.w;
  u16 h0 = f2bf(o0), h1 = f2bf(o1), h2 = f2bf(o2), h3 = f2bf(o3);
  uint2 hw = {(unsigned)h0 | ((unsigned)h1 << 16), (unsigned)h2 | ((unsigned)h3 << 16)};
  uint2 lw = {pack2(o0 - bf2f(h0), o1 - bf2f(h1)), pack2(o2 - bf2f(h2), o3 - bf2f(h3))};
  *reinterpret_cast<uint2*>(xh + (size_t)row * Dm + t * 4) = hw;
  *reinterpret_cast<uint2*>(xl + (size_t)row * Dm + t * 4) = lw;
}

// ------------- weight convert: w[K=1024][N] fp32 -> wt_h/wt_l [N][1024] bf16 -------------
__global__ __launch_bounds__(256) void convert_w(
    const float* __restrict__ w, u16* __restrict__ wh, u16* __restrict__ wl, int N) {
  __shared__ float T[64][65];
  const int n0 = blockIdx.x * 64, k0 = blockIdx.y * 64;
  const int t = threadIdx.x;
#pragma unroll
  for (int p = 0; p < 4; ++p) {
    int fid = p * 256 + t;
    int kr = fid >> 4, nn = (fid & 15) * 4;
    float4 v = *reinterpret_cast<const float4*>(w + (size_t)(k0 + kr) * N + n0 + nn);
    T[kr][nn] = v.x; T[kr][nn + 1] = v.y; T[kr][nn + 2] = v.z; T[kr][nn + 3] = v.w;
  }
  __syncthreads();
  const int n = t >> 2, kc = (t & 3) * 16;
  unsigned int hw[8], lw[8];
#pragma unroll
  for (int i = 0; i < 8; ++i) {
    float v0 = T[kc + 2 * i][n], v1 = T[kc + 2 * i + 1][n];
    u16 a = f2bf(v0), b = f2bf(v1);
    hw[i] = (unsigned)a | ((unsigned)b << 16);
    lw[i] = pack2(v0 - bf2f(a), v1 - bf2f(b));
  }
  size_t o = (size_t)(n0 + n) * 1024 + k0 + kc;
  *reinterpret_cast<uint4*>(wh + o) = *reinterpret_cast<uint4*>(&hw[0]);
  *reinterpret_cast<uint4*>(wh + o + 8) = *reinterpret_cast<uint4*>(&hw[4]);
  *reinterpret_cast<uint4*>(wl + o) = *reinterpret_cast<uint4*>(&lw[0]);
  *reinterpret_cast<uint4*>(wl + o + 8) = *reinterpret_cast<uint4*>(&lw[4]);
}

// ---------------- split-bf16 MFMA GEMM, m97 structure ----------------
// C = Ah@Bh + Ah@Bl + Al@Bh (drops Al@Bl). global_load_lds staging, BK=32,
// LDS tiles row-major [rows][32] bf16 (64B rows): gload dest linear, frag
// ds_read_b128 covers a contiguous 1KB range per wave (conflict-free).
// 4 waves in 2x2; wave tile (BM/2)x(BN/2) of 16x16 frags.
template <int BM, int BN, int N, int MODE>
__global__ __launch_bounds__(256) void gemm_mfma(
    const u16* __restrict__ Ahg, const u16* __restrict__ Alg,
    const u16* __restrict__ Bhg, const u16* __restrict__ Blg,
    float* __restrict__ oF, u16* __restrict__ qq, u16* __restrict__ kk,
    u16* __restrict__ vv, const float* __restrict__ bias) {
  constexpr int MF = BM / 32;  // m-frags per wave
  constexpr int NF = BN / 32;  // n-frags per wave
  constexpr int AI = BM / 64;  // gload insts per wave per A tile
  constexpr int BI = BN / 64;
  __shared__ __align__(16) u16 Ah[BM * 32], Al[BM * 32], Bh[BN * 32], Bl[BN * 32];
  const int tid = threadIdx.x;
  const int bn = blockIdx.x, bm = blockIdx.y;
  const int wv = tid >> 6, lane = tid & 63;
  const int qn = lane & 15, g = lane >> 4;
  const int wr = wv >> 1, wc = wv & 1;
  const int m0 = bm * BM, n0 = bn * BN;
  const int r4 = lane >> 2, c4 = lane & 3;  // staging: slot row / 8-elem chunk

  f32x4 acc[MF][NF];
#pragma unroll
  for (int m = 0; m < MF; ++m)
#pragma unroll
    for (int n = 0; n < NF; ++n) acc[m][n] = (f32x4){0.f, 0.f, 0.f, 0.f};

  for (int kt = 0; kt < Dm / 32; ++kt) {
    const int k0 = kt * 32;
#pragma unroll
    for (int j = 0; j < AI; ++j) {
      const int sl = wv * AI + j;  // 64-slot group; dest uniform per wave
      const size_t go = (size_t)(m0 + sl * 16 + r4) * Dm + k0 + c4 * 8;
      gload16(&Ah[sl * 512], Ahg + go);
      gload16(&Al[sl * 512], Alg + go);
    }
#pragma unroll
    for (int j = 0; j < BI; ++j) {
      const int sl = wv * BI + j;
      const size_t go = (size_t)(n0 + sl * 16 + r4) * Dm + k0 + c4 * 8;
      gload16(&Bh[sl * 512], Bhg + go);
      gload16(&Bl[sl * 512], Blg + go);
    }
    __syncthreads();  // drains vmcnt (gload_lds) before reads
    bf16x8 af[2][MF], bb[2][NF];
#pragma unroll
    for (int m = 0; m < MF; ++m) {
      const int ro = (wr * (BM / 2) + m * 16 + qn) * 32 + g * 8;
      af[0][m] = *reinterpret_cast<const bf16x8*>(&Ah[ro]);
      af[1][m] = *reinterpret_cast<const bf16x8*>(&Al[ro]);
    }
#pragma unroll
    for (int n = 0; n < NF; ++n) {
      const int ro = (wc * (BN / 2) + n * 16 + qn) * 32 + g * 8;
      bb[0][n] = *reinterpret_cast<const bf16x8*>(&Bh[ro]);
      bb[1][n] = *reinterpret_cast<const bf16x8*>(&Bl[ro]);
    }
#pragma unroll
    for (int m = 0; m < MF; ++m)
#pragma unroll
      for (int n = 0; n < NF; ++n) {
        acc[m][n] = __builtin_amdgcn_mfma_f32_16x16x32_bf16(af[0][m], bb[0][n], acc[m][n], 0, 0, 0);
        acc[m][n] = __builtin_amdgcn_mfma_f32_16x16x32_bf16(af[0][m], bb[1][n], acc[m][n], 0, 0, 0);
        acc[m][n] = __builtin_amdgcn_mfma_f32_16x16x32_bf16(af[1][m], bb[0][n], acc[m][n], 0, 0, 0);
      }
    __syncthreads();  // all reads done before next staging overwrite
  }

  if (MODE == 0) {
    const int which = n0 >> 10;  // BN=128 tile never straddles q/k/v
#pragma unroll
    for (int n = 0; n < NF; ++n) {
      const int c = n0 + wc * (BN / 2) + n * 16 + qn;
      const int d = c & 1023, h = d >> 6, dh = d & 63;
#pragma unroll
      for (int m = 0; m < MF; ++m) {
        const int mr0 = m0 + wr * (BM / 2) + m * 16 + 4 * g;
        const int bb2 = mr0 >> 11, ss = mr0 & 2047;
        if (which == 2) {
          uint2 w = {pack2(acc[m][n][0], acc[m][n][1]),
                     pack2(acc[m][n][2], acc[m][n][3])};
          *reinterpret_cast<uint2*>(&vv[(((size_t)bb2 * Hh + h) * Dh + dh) * Sq + ss]) = w;
        } else {
          u16* dst = (which == 0) ? qq : kk;
          const float sc = (which == 0) ? 0.125f : 1.0f;
#pragma unroll
          for (int r = 0; r < 4; ++r)
            dst[(((size_t)bb2 * Hh + h) * Sq + (ss + r)) * Dh + dh] =
                f2bf(acc[m][n][r] * sc);
        }
      }
    }
  } else {
#pragma unroll
    for (int n = 0; n < NF; ++n) {
      const int c = n0 + wc * (BN / 2) + n * 16 + qn;
      const float bv = bias[c];
#pragma unroll
      for (int m = 0; m < MF; ++m) {
        const int mr0 = m0 + wr * (BM / 2) + m * 16 + 4 * g;
#pragma unroll
        for (int r = 0; r < 4; ++r)
          oF[(size_t)(mr0 + r) * N + c] = acc[m][n][r] + bv;
      }
    }
  }
}

// ---------------- swapped-operand 32x32 MFMA flash attention ----------------
// Zero LDS, zero barriers. 4 waves x 32 q-rows; KVBLK=64 (two 32-row subtiles).
// S^T = K.Q^T via mfma(K-rows, Q-rows): lane holds scores of ONE q-row (q=ln31)
// at k = (reg&3)+8*(reg>>2)+4*half -> softmax is in-lane + one shfl_xor(32).
// P^T B-frags built in-register via cvt_pk + shfl_xor(32) exchange.
// PV computes O^T = V^T.P^T (Vt layout [B,H,64,S] gives contiguous V frags).
__global__ __launch_bounds__(256, 2) void attn_mfma32(
    const u16* __restrict__ Q, const u16* __restrict__ K,
    const u16* __restrict__ Vt, u16* __restrict__ Oh, u16* __restrict__ Ol) {
  const int tid = threadIdx.x;
  const int wv = tid >> 6, lane = tid & 63;
  const int ln31 = lane & 31, half = lane >> 5;
  // T1 bijective XCD swizzle: 512 wgs, chunks of 64 -> each XCD sees 4 heads
  const int n = (blockIdx.x & 7) * 64 + (blockIdx.x >> 3);
  const int bh = n >> 4, qt = n & 15;
  const int q0 = qt * 128 + wv * 32;
  const u16* Qb = Q + ((size_t)bh * Sq + q0) * Dh;
  const u16* Kb = K + (size_t)bh * Sq * Dh;
  const u16* Vb = Vt + (size_t)bh * Dh * Sq;

  // Q fragments (B-operand: rows = q, contraction = 8*half+i), 4 d-chunks
  bf16x8 qf[4];
#pragma unroll
  for (int c = 0; c < 4; ++c)
    qf[c] = *reinterpret_cast<const bf16x8*>(Qb + ln31 * Dh + c * 16 + 8 * half);

  f32x16 o0, o1;  // O^T accumulators: dh 0-31 / 32-63, col = own q
#pragma unroll
  for (int j = 0; j < 16; ++j) { o0[j] = 0.f; o1[j] = 0.f; }
  float mrun = -1e30f, lrun = 0.f;

  // K fragments for kt=0
  bf16x8 kf[2][4];
#pragma unroll
  for (int sub = 0; sub < 2; ++sub)
#pragma unroll
    for (int c = 0; c < 4; ++c)
      kf[sub][c] = *reinterpret_cast<const bf16x8*>(
          Kb + (size_t)(sub * 32 + ln31) * Dh + c * 16 + 8 * half);

  for (int kt = 0; kt < Sq / 64; ++kt) {
    // QK^T: s_sub[reg] = S[k = 64kt+32sub+(reg&3)+8(reg>>2)+4half][q = ln31]
    f32x16 s0, s1;
#pragma unroll
    for (int j = 0; j < 16; ++j) { s0[j] = 0.f; s1[j] = 0.f; }
#pragma unroll
    for (int c = 0; c < 4; ++c) {
      s0 = __builtin_amdgcn_mfma_f32_32x32x16_bf16(kf[0][c], qf[c], s0, 0, 0, 0);
      s1 = __builtin_amdgcn_mfma_f32_32x32x16_bf16(kf[1][c], qf[c], s1, 0, 0, 0);
    }
    // V fragments (in flight during softmax)
    bf16x8 vf[2][4];
#pragma unroll
    for (int h2 = 0; h2 < 2; ++h2)
#pragma unroll
      for (int c = 0; c < 4; ++c)
        vf[h2][c] = *reinterpret_cast<const bf16x8*>(
            Vb + (size_t)(h2 * 32 + ln31) * Sq + kt * 64 + c * 16 + 8 * half);
    // online softmax: in-lane over 32 + one cross-half exchange
    float mx = s0[0];
#pragma unroll
    for (int j = 1; j < 16; ++j) mx = fmaxf(mx, s0[j]);
#pragma unroll
    for (int j = 0; j < 16; ++j) mx = fmaxf(mx, s1[j]);
    mx = fmaxf(mx, __shfl_xor(mx, 32));
    float mnew = fmaxf(mrun, mx);
    float corr = __expf(mrun - mnew);
    float sum = 0.f;
#pragma unroll
    for (int j = 0; j < 16; ++j) { float e = __expf(s0[j] - mnew); s0[j] = e; sum += e; }
#pragma unroll
    for (int j = 0; j < 16; ++j) { float e = __expf(s1[j] - mnew); s1[j] = e; sum += e; }
    sum += __shfl_xor(sum, 32);
    lrun = lrun * corr + sum;
    mrun = mnew;
#pragma unroll
    for (int j = 0; j < 16; ++j) { o0[j] *= corr; o1[j] *= corr; }
    // P^T -> bf16 B-fragments (chunk c covers k = c*16..c*16+15)
    int dw[4][4];
    mk_frag<0>(s0, half, dw[0]);
    mk_frag<8>(s0, half, dw[1]);
    mk_frag<0>(s1, half, dw[2]);
    mk_frag<8>(s1, half, dw[3]);
    // prefetch K for kt+1 (hidden under PV MFMAs)
    if (kt + 1 < Sq / 64) {
      const u16* Kn = Kb + (size_t)(kt + 1) * 64 * Dh;
#pragma unroll
      for (int sub = 0; sub < 2; ++sub)
#pragma unroll
        for (int c = 0; c < 4; ++c)
          kf[sub][c] = *reinterpret_cast<const bf16x8*>(
              Kn + (size_t)(sub * 32 + ln31) * Dh + c * 16 + 8 * half);
    }
    // PV: O^T += V^T . P^T
#pragma unroll
    for (int c = 0; c < 4; ++c) {
      union { int4 i; bf16x8 b; } u;
      u.i = make_int4(dw[c][0], dw[c][1], dw[c][2], dw[c][3]);
      o0 = __builtin_amdgcn_mfma_f32_32x32x16_bf16(vf[0][c], u.b, o0, 0, 0, 0);
      o1 = __builtin_amdgcn_mfma_f32_32x32x16_bf16(vf[1][c], u.b, o1, 0, 0, 0);
    }
  }

  // epilogue: lane owns q = ln31, dh rows h2*32 + 8rg + 4half (+0..3)
  const float inv = 1.0f / lrun;
  const int b = bh >> 4, hh = bh & 15;
  u16* oph = Oh + ((size_t)(b * Sq) + q0 + ln31) * Dm + hh * 64;
  u16* opl = Ol + ((size_t)(b * Sq) + q0 + ln31) * Dm + hh * 64;
#pragma unroll
  for (int h2 = 0; h2 < 2; ++h2) {
#pragma unroll
    for (int rg = 0; rg < 4; ++rg) {
      const int dh = h2 * 32 + 8 * rg + 4 * half;
      float v0, v1, v2, v3;
      if (h2 == 0) {
        v0 = o0[4 * rg] * inv; v1 = o0[4 * rg + 1] * inv;
        v2 = o0[4 * rg + 2] * inv; v3 = o0[4 * rg + 3] * inv;
      } else {
        v0 = o1[4 * rg] * inv; v1 = o1[4 * rg + 1] * inv;
        v2 = o1[4 * rg + 2] * inv; v3 = o1[4 * rg + 3] * inv;
      }
      u16 h0 = f2bf(v0), h1 = f2bf(v1), h2b = f2bf(v2), h3 = f2bf(v3);
      uint2 hw = {(unsigned)h0 | ((unsigned)h1 << 16),
                  (unsigned)h2b | ((unsigned)h3 << 16)};
      uint2 lw = {pack2(v0 - bf2f(h0), v1 - bf2f(h1)),
                  pack2(v2 - bf2f(h2b), v3 - bf2f(h3))};
      *reinterpret_cast<uint2*>(oph + dh) = hw;
      *reinterpret_cast<uint2*>(opl + dh) = lw;
    }
  }
}

extern "C" void kernel_launch(void* const* d_in, const int* in_sizes, int n_in,
                              void* d_out, int out_size, void* d_ws, size_t ws_size,
                              hipStream_t stream) {
  const float* x = (const float*)d_in[0];
  const float* gamma = (const float*)d_in[1];
  const float* beta = (const float*)d_in[2];
  const float* w_qkv = (const float*)d_in[3];
  const float* w_out = (const float*)d_in[4];
  const float* b_out = (const float*)d_in[5];
  float* out = (float*)d_out;
  u16* W = (u16*)d_ws;
  const size_t NT = (size_t)Rows * Dm;  // 4M elems
  const size_t MT = (size_t)Dm * Dm;    // 1M elems
  u16* xh = W;
  u16* xl = W + NT;
  u16* Qbf = W + 2 * NT;     // [B,H,S,64], x0.125
  u16* Kbf = W + 3 * NT;     // [B,H,S,64]
  u16* Vbf = W + 4 * NT;     // [B,H,64,S]
  u16* Ohh = W + 5 * NT;     // attn out hi [4096,1024]
  u16* Oll = W + 6 * NT;     // attn out lo
  u16* wqh = W + 7 * NT;     // [3072,1024]
  u16* wql = wqh + 3 * MT;
  u16* woh = wql + 3 * MT;   // [1024,1024]
  u16* wol = woh + MT;

  convert_w<<<dim3(48, 16), dim3(256), 0, stream>>>(w_qkv, wqh, wql, 3072);
  convert_w<<<dim3(16, 16), dim3(256), 0, stream>>>(w_out, woh, wol, 1024);
  ln_kernel<<<dim3(Rows), dim3(256), 0, stream>>>(x, gamma, beta, xh, xl);
  gemm_mfma<128, 128, 3072, 0><<<dim3(24, 32), dim3(256), 0, stream>>>(
      xh, xl, wqh, wql, nullptr, Qbf, Kbf, Vbf, nullptr);
  attn_mfma32<<<dim3(512), dim3(256), 0, stream>>>(Qbf, Kbf, Vbf, Ohh, Oll);
  gemm_mfma<128, 64, 1024, 1><<<dim3(16, 32), dim3(256), 0, stream>>>(
      Ohh, Oll, woh, wol, out, nullptr, nullptr, nullptr, b_out);
}